// Round 4
// baseline (424.649 us; speedup 1.0000x reference)
//
#include <hip/hip_runtime.h>

#define IN_H 256
#define IN_W 256
#define C0   3
#define C1   32
#define H1   128
#define C2   64
#define H2   64
#define NB   32
#define K_FLAT (H2*H2*C2)   // 262144
#define NHID 128

// a1 layout: [b][y 128][parity 2][ci 32][x2 64]  (x = 2*x2 + parity)
// -> conv2 reads per (tap, ci) are lane-contiguous (2 cache lines/instr
//    instead of the 64-line gathers NHWC gave us in R3).
#define A1_IDX(b,y,p,ci,x2) (((((size_t)(b)*H1 + (y))*2 + (p))*C1 + (ci))*64 + (x2))

// ---------------------------------------------------------------- conv1
// in [32,256,256,3] -> a1p (planar layout above), stride2 SAME, ReLU.
// co split 2-way (cg16 per wave-pair) -> acc[16], coalesced per-co stores.
__global__ __launch_bounds__(256)
void conv1_k(const float* __restrict__ in, const float* __restrict__ k1,
             const float* __restrict__ b1, float* __restrict__ a1p) {
  const int tid = threadIdx.x;
  const int ox  = tid & 127;                                    // 0..127
  const int cg  = __builtin_amdgcn_readfirstlane((tid >> 7) * 16); // 0 or 16
  const int oy  = blockIdx.x;       // 0..127
  const int b   = blockIdx.y;       // 0..31

  float acc[16];
#pragma unroll
  for (int co = 0; co < 16; ++co) acc[co] = b1[cg + co];

#pragma unroll
  for (int dy = 0; dy < 3; ++dy) {
    const int iy  = 2*oy + dy;
    const bool rok = iy < IN_H;
    const int iyc = rok ? iy : (IN_H-1);
#pragma unroll
    for (int dx = 0; dx < 3; ++dx) {
      const int ix  = 2*ox + dx;
      const bool ok = rok && (ix < IN_W);
      const int ixc = (ix < IN_W) ? ix : (IN_W-1);
      const float* ip = in + ((size_t)(b*IN_H + iyc)*IN_W + ixc)*C0;
      const float v0 = ok ? ip[0] : 0.f;
      const float v1 = ok ? ip[1] : 0.f;
      const float v2 = ok ? ip[2] : 0.f;
      const float* wp = k1 + (size_t)((dy*3+dx)*C0)*C1 + cg;   // [ci][co]
#pragma unroll
      for (int co = 0; co < 16; ++co)
        acc[co] = fmaf(v0, wp[co],
                  fmaf(v1, wp[C1+co],
                  fmaf(v2, wp[2*C1+co], acc[co])));
    }
  }
  const int p  = ox & 1;
  const int x2 = ox >> 1;
#pragma unroll
  for (int co = 0; co < 16; ++co)
    a1p[A1_IDX(b, oy, p, cg + co, x2)] = fmaxf(acc[co], 0.f);
}

// ---------------------------------------------------------------- conv2
// a1p (planar) -> a2 [32,64,64,64] NHWC, stride2 SAME, ReLU.
// Block = [cg 4][ox 64]; acc[16] (R2 lesson: ~60-VGPR budget, bigger acc
// spills). Input loads fully lane-coalesced via the planar layout:
//   x = 2*ox+dx -> parity dx&1, x2 = ox + (dx>>1).
// Taps fully unrolled so uniform weight s_loads pipeline across taps.
__global__ __launch_bounds__(256)
void conv2_k(const float* __restrict__ a1p, const float* __restrict__ k2,
             const float* __restrict__ b2, float* __restrict__ a2) {
  const int tid = threadIdx.x;
  const int ox  = tid & 63;                                        // 0..63
  const int cg16 = __builtin_amdgcn_readfirstlane((tid >> 6) * 16); // co base
  const int oy  = blockIdx.x;                                      // 0..63
  const int b   = blockIdx.y;

  float acc[16];
#pragma unroll
  for (int co = 0; co < 16; ++co) acc[co] = b2[cg16 + co];

#pragma unroll
  for (int dy = 0; dy < 3; ++dy) {
    const int iy  = 2*oy + dy;
    const bool rok = iy < H1;
    const int iyc = rok ? iy : (H1-1);
#pragma unroll
    for (int dx = 0; dx < 3; ++dx) {
      const int p   = dx & 1;
      const int x2  = ox + (dx >> 1);
      const bool ok = rok && (x2 < 64);
      const int x2c = (x2 < 64) ? x2 : 63;
      const float* ip = a1p + A1_IDX(b, iyc, p, 0, x2c);   // +ci*64 per channel
      const float* wp = k2 + (size_t)((dy*3+dx)*C1)*C2 + cg16;
#pragma unroll
      for (int ci = 0; ci < C1; ++ci) {
        float v = ip[(size_t)ci*64];
        v = ok ? v : 0.f;
        const float* wr = wp + (size_t)ci*C2;
#pragma unroll
        for (int co = 0; co < 16; ++co) acc[co] = fmaf(v, wr[co], acc[co]);
      }
    }
  }
  float* op = a2 + ((size_t)(b*H2 + oy)*H2 + ox)*C2 + cg16;
#pragma unroll
  for (int g = 0; g < 4; ++g) {
    float4 o;
    o.x = fmaxf(acc[4*g+0], 0.f);
    o.y = fmaxf(acc[4*g+1], 0.f);
    o.z = fmaxf(acc[4*g+2], 0.f);
    o.w = fmaxf(acc[4*g+3], 0.f);
    ((float4*)op)[g] = o;
  }
}

// ---------------------------------------------------------------- FC1 partial
// x = a2 flat [32, 262144]; w1 [262144, 128]. 1024 blocks, each owns a 256-k
// span. x chunk staged transposed in LDS (pad 36). Threads = [q 32 n-quads]
// [bo 8 b-quads]; acc = [4b][4n] = 16 regs -> no spill at the 64-VGPR budget.
#define FC1_G   1024
#define KSPAN   (K_FLAT / FC1_G)   // 256

__global__ __launch_bounds__(256)
void fc1_partial_k(const float* __restrict__ a2, const float* __restrict__ w1,
                   float* __restrict__ partial) {
  __shared__ __align__(16) float xT[KSPAN*36];   // 36,864 B
  const int tid = threadIdx.x;
  const int q   = tid & 31;    // n-quad: n = 4q..4q+3
  const int bo  = tid >> 5;    // 0..7 : b = 4bo..4bo+3
  const int k0  = blockIdx.x * KSPAN;

  // stage x chunk transposed: xT[k][b]
  {
    const int lb  = tid >> 3;    // 0..31
    const int lkq = tid & 7;
#pragma unroll
    for (int j = 0; j < 8; ++j) {
      const int k4 = lkq*4 + j*32;
      float4 t = *(const float4*)(a2 + (size_t)lb*K_FLAT + k0 + k4);
      xT[(k4+0)*36 + lb] = t.x;
      xT[(k4+1)*36 + lb] = t.y;
      xT[(k4+2)*36 + lb] = t.z;
      xT[(k4+3)*36 + lb] = t.w;
    }
  }
  __syncthreads();

  float4 a0 = make_float4(0.f,0.f,0.f,0.f), a1v = a0, a2v = a0, a3v = a0;
#pragma unroll 4
  for (int k = 0; k < KSPAN; ++k) {
    const float4 w4 = *(const float4*)(w1 + (size_t)(k0 + k)*NHID + 4*q);
    const float4 xb = *(const float4*)&xT[k*36 + 4*bo];
    a0.x = fmaf(xb.x, w4.x, a0.x); a0.y = fmaf(xb.x, w4.y, a0.y);
    a0.z = fmaf(xb.x, w4.z, a0.z); a0.w = fmaf(xb.x, w4.w, a0.w);
    a1v.x = fmaf(xb.y, w4.x, a1v.x); a1v.y = fmaf(xb.y, w4.y, a1v.y);
    a1v.z = fmaf(xb.y, w4.z, a1v.z); a1v.w = fmaf(xb.y, w4.w, a1v.w);
    a2v.x = fmaf(xb.z, w4.x, a2v.x); a2v.y = fmaf(xb.z, w4.y, a2v.y);
    a2v.z = fmaf(xb.z, w4.z, a2v.z); a2v.w = fmaf(xb.z, w4.w, a2v.w);
    a3v.x = fmaf(xb.w, w4.x, a3v.x); a3v.y = fmaf(xb.w, w4.y, a3v.y);
    a3v.z = fmaf(xb.w, w4.z, a3v.z); a3v.w = fmaf(xb.w, w4.w, a3v.w);
  }

  float* pp = partial + (size_t)blockIdx.x*(NB*NHID) + 4*q;
  *(float4*)(pp + (4*bo+0)*NHID) = a0;
  *(float4*)(pp + (4*bo+1)*NHID) = a1v;
  *(float4*)(pp + (4*bo+2)*NHID) = a2v;
  *(float4*)(pp + (4*bo+3)*NHID) = a3v;
}

// ---------------------------------------------------------------- FC1 reduce stage 1: 1024 -> 8
__global__ __launch_bounds__(128)
void fc1_reduce1_k(const float* __restrict__ partial, float* __restrict__ partial2) {
  const int t  = blockIdx.x*128 + threadIdx.x;  // 0..4095
  const int gc = blockIdx.y;                    // 0..7
  float s = 0.f;
#pragma unroll 8
  for (int g = gc*128; g < gc*128+128; ++g) s += partial[(size_t)g*(NB*NHID) + t];
  partial2[(size_t)gc*(NB*NHID) + t] = s;
}

// ---------------------------------------------------------------- FC1 reduce stage 2 (+bias+ReLU)
__global__ __launch_bounds__(256)
void fc1_reduce2_k(const float* __restrict__ partial2, const float* __restrict__ d1,
                   float* __restrict__ h) {
  const int t = blockIdx.x*256 + threadIdx.x;  // 0..4095
  float s = 0.f;
#pragma unroll
  for (int gc = 0; gc < 8; ++gc) s += partial2[(size_t)gc*(NB*NHID) + t];
  h[t] = fmaxf(s + d1[t & (NHID-1)], 0.f);
}

// ---------------------------------------------------------------- theta = h @ w2 + d2
__global__ __launch_bounds__(192)
void theta_k(const float* __restrict__ h, const float* __restrict__ w2,
             const float* __restrict__ d2, float* __restrict__ theta) {
  const int t = threadIdx.x;
  if (t >= NB*6) return;
  const int b = t / 6, j = t % 6;
  float s0 = 0.f, s1 = 0.f, s2 = 0.f, s3 = 0.f;
  for (int n = 0; n < NHID; n += 4) {
    s0 = fmaf(h[b*NHID + n+0], w2[(n+0)*6 + j], s0);
    s1 = fmaf(h[b*NHID + n+1], w2[(n+1)*6 + j], s1);
    s2 = fmaf(h[b*NHID + n+2], w2[(n+2)*6 + j], s2);
    s3 = fmaf(h[b*NHID + n+3], w2[(n+3)*6 + j], s3);
  }
  theta[t] = (s0 + s1) + (s2 + s3) + d2[j];
}

// ---------------------------------------------------------------- grid sample (bilinear, zero pad)
__global__ __launch_bounds__(256)
void sample_k(const float* __restrict__ img, const float* __restrict__ theta,
              float* __restrict__ out) {
  const int x = threadIdx.x;
  const int y = blockIdx.x & (IN_H-1);
  const int b = blockIdx.x >> 8;
  const float* tp = theta + b*6;
  const float t0 = tp[0], t1 = tp[1], t2 = tp[2];
  const float t3 = tp[3], t4 = tp[4], t5 = tp[5];

  const float xs = (2.f*x + 1.f)*(1.f/IN_W) - 1.f;
  const float ys = (2.f*y + 1.f)*(1.f/IN_H) - 1.f;
  const float gx = fmaf(t0, xs, fmaf(t1, ys, t2));
  const float gy = fmaf(t3, xs, fmaf(t4, ys, t5));
  const float px = fmaf(gx + 1.f, 0.5f*IN_W, -0.5f);
  const float py = fmaf(gy + 1.f, 0.5f*IN_H, -0.5f);

  const float x0f = floorf(px), y0f = floorf(py);
  const int ix0 = (int)x0f, iy0 = (int)y0f;
  const float wx1 = px - x0f, wx0 = 1.f - wx1;
  const float wy1 = py - y0f, wy0 = 1.f - wy1;

  float r = 0.f, g = 0.f, bl = 0.f;
  const float* ib = img + (size_t)b*IN_H*IN_W*C0;

  auto tap = [&](int yi, int xi, float w) {
    const bool v = (xi >= 0) && (xi < IN_W) && (yi >= 0) && (yi < IN_H);
    const int xc = xi < 0 ? 0 : (xi > IN_W-1 ? IN_W-1 : xi);
    const int yc = yi < 0 ? 0 : (yi > IN_H-1 ? IN_H-1 : yi);
    const float* p = ib + ((size_t)yc*IN_W + xc)*C0;
    if (v) {
      r  = fmaf(w, p[0], r);
      g  = fmaf(w, p[1], g);
      bl = fmaf(w, p[2], bl);
    }
  };
  tap(iy0,   ix0,   wy0*wx0);
  tap(iy0,   ix0+1, wy0*wx1);
  tap(iy0+1, ix0,   wy1*wx0);
  tap(iy0+1, ix0+1, wy1*wx1);

  float* op = out + ((size_t)(b*IN_H + y)*IN_W + x)*C0;
  op[0] = r; op[1] = g; op[2] = bl;
}

// ---------------------------------------------------------------- launch
extern "C" void kernel_launch(void* const* d_in, const int* in_sizes, int n_in,
                              void* d_out, int out_size, void* d_ws, size_t ws_size,
                              hipStream_t stream) {
  const float* in = (const float*)d_in[0];
  const float* k1 = (const float*)d_in[1];
  const float* b1 = (const float*)d_in[2];
  const float* k2 = (const float*)d_in[3];
  const float* b2 = (const float*)d_in[4];
  const float* w1 = (const float*)d_in[5];
  const float* d1 = (const float*)d_in[6];
  const float* w2 = (const float*)d_in[7];
  const float* d2 = (const float*)d_in[8];
  float* out = (float*)d_out;
  float* ws  = (float*)d_ws;

  // ws layout (float offsets):
  //   a1p      [16,777,216] @ 0               (planar layout)
  //   a2       [ 8,388,608] @ 16,777,216      (NHWC, matches flatten order)
  //   -- after conv2, a1p region is dead and reused: --
  //   partial  [1024*4096 = 4,194,304] @ 0
  //   partial2 [8*4096    =    32,768] @ 4,194,304
  //   h        [4096]                  @ 4,227,072
  //   theta    [192]                   @ 4,231,168
  float* a1p     = ws;
  float* a2      = ws + (size_t)16777216;
  float* partial = ws;
  float* part2   = ws + (size_t)4194304;
  float* h       = ws + (size_t)4227072;
  float* th      = ws + (size_t)4231168;

  hipLaunchKernelGGL(conv1_k,       dim3(128, 32), dim3(256), 0, stream, in, k1, b1, a1p);
  hipLaunchKernelGGL(conv2_k,       dim3(64, 32),  dim3(256), 0, stream, a1p, k2, b2, a2);
  hipLaunchKernelGGL(fc1_partial_k, dim3(FC1_G),   dim3(256), 0, stream, a2, w1, partial);
  hipLaunchKernelGGL(fc1_reduce1_k, dim3(32, 8),   dim3(128), 0, stream, partial, part2);
  hipLaunchKernelGGL(fc1_reduce2_k, dim3(16),      dim3(256), 0, stream, part2, d1, h);
  hipLaunchKernelGGL(theta_k,       dim3(1),       dim3(192), 0, stream, h, w2, d2, th);
  hipLaunchKernelGGL(sample_k,      dim3(NB*IN_H), dim3(256), 0, stream, in, th, out);
}

// Round 5
// 388.971 us; speedup vs baseline: 1.0917x; 1.0917x over previous
//
#include <hip/hip_runtime.h>

#define IN_H 256
#define IN_W 256
#define C0   3
#define C1   32
#define H1   128
#define C2   64
#define H2   64
#define NB   32
#define K_FLAT (H2*H2*C2)   // 262144
#define NHID 128

// a1 layout: [b][parity 2][y 128][ci 32][x2 64], x = 2*x2 + parity.
// conv2's per-(tap,ci) read is then 64 lanes x 4B contiguous (1 instr, 2-3
// cache lines) instead of NHWC's 64-line gather (R3) and with NO per-lane
// boundary selects in the inner loop (R4's codegen pathology trigger).
#define A1_IDX(b,p,y,ci,x2) ((((((size_t)(b)*2 + (p))*H1 + (y))*C1 + (ci))*64) + (x2))

// ---------------------------------------------------------------- conv1
// in [32,256,256,3] -> a1p (planar layout above), stride2 SAME, ReLU.
// co split 2-way (cg per half-block) -> acc[16]. Per-co stores coalesce into
// 2x128B segments per wave.
__global__ __launch_bounds__(256)
void conv1_k(const float* __restrict__ in, const float* __restrict__ k1,
             const float* __restrict__ b1, float* __restrict__ a1p) {
  const int tid = threadIdx.x;
  const int ox  = tid & 127;                                       // 0..127
  const int cg  = __builtin_amdgcn_readfirstlane((tid >> 7) * 16); // 0 or 16
  const int oy  = blockIdx.x;       // 0..127
  const int b   = blockIdx.y;       // 0..31

  float acc[16];
#pragma unroll
  for (int co = 0; co < 16; ++co) acc[co] = b1[cg + co];

#pragma unroll
  for (int dy = 0; dy < 3; ++dy) {
    const int iy  = 2*oy + dy;
    if (iy >= IN_H) continue;        // block-uniform for oy==127
#pragma unroll
    for (int dx = 0; dx < 3; ++dx) {
      const int ix  = 2*ox + dx;
      const bool ok = ix < IN_W;     // per-lane only for ox==127, dx==2
      const int ixc = ok ? ix : (IN_W-1);
      const float* ip = in + ((size_t)(b*IN_H + iy)*IN_W + ixc)*C0;
      const float m  = ok ? 1.f : 0.f;
      const float v0 = ip[0] * m;
      const float v1 = ip[1] * m;
      const float v2 = ip[2] * m;
      const float* wp = k1 + (size_t)((dy*3+dx)*C0)*C1 + cg;   // [ci][co]
#pragma unroll
      for (int co = 0; co < 16; ++co)
        acc[co] = fmaf(v0, wp[co],
                  fmaf(v1, wp[C1+co],
                  fmaf(v2, wp[2*C1+co], acc[co])));
    }
  }
  const int p  = ox & 1;
  const int x2 = ox >> 1;
#pragma unroll
  for (int co = 0; co < 16; ++co)
    a1p[A1_IDX(b, p, oy, cg + co, x2)] = fmaxf(acc[co], 0.f);
}

// ---------------------------------------------------------------- conv2
// a1p (planar) -> a2 [32,64,64,64] NHWC, stride2 SAME, ReLU.
// Block = [cg 4][ox 64]; acc[16] (60-VGPR-budget lesson, R2). Inner loop is
// select-free: y-boundary is a block-uniform branch, x-boundary (lane 63,
// dx=2) is one mask-multiply per (dy,ci). 3 coalesced loads + 48 FMA per
// (dy,ci); weights wave-uniform -> s_load + SGPR-operand FMA.
__global__ __launch_bounds__(256)
void conv2_k(const float* __restrict__ a1p, const float* __restrict__ k2,
             const float* __restrict__ b2, float* __restrict__ a2) {
  const int tid = threadIdx.x;
  const int ox  = tid & 63;                                        // 0..63
  const int cg16 = __builtin_amdgcn_readfirstlane((tid >> 6) * 16); // co base
  const int oy  = blockIdx.x;                                      // 0..63
  const int b   = blockIdx.y;

  float acc[16];
#pragma unroll
  for (int co = 0; co < 16; ++co) acc[co] = b2[cg16 + co];

  const float xm = (ox == 63) ? 0.f : 1.f;   // dx=2 x-boundary mask

#pragma unroll
  for (int dy = 0; dy < 3; ++dy) {
    const int iy = 2*oy + dy;
    if (iy >= H1) continue;                  // block-uniform for oy==63
    const float* r0 = a1p + A1_IDX(b, 0, iy, 0, 0) + ox;  // dx=0 / dx=2 plane
    const float* r1 = a1p + A1_IDX(b, 1, iy, 0, 0) + ox;  // dx=1 plane
    const float* wp = k2 + (size_t)(dy*3*C1)*C2 + cg16;   // [dx][ci][co]
#pragma unroll 4
    for (int ci = 0; ci < C1; ++ci) {
      const float v0 = r0[(size_t)ci*64];          // x = 2ox   (p0, x2=ox)
      const float v1 = r1[(size_t)ci*64];          // x = 2ox+1 (p1, x2=ox)
      const float v2 = r0[(size_t)ci*64 + 1] * xm; // x = 2ox+2 (p0, x2=ox+1)
      const float* w0 = wp + (size_t)ci*C2;
      const float* w1r = wp + (size_t)(C1 + ci)*C2;
      const float* w2r = wp + (size_t)(2*C1 + ci)*C2;
#pragma unroll
      for (int co = 0; co < 16; ++co)
        acc[co] = fmaf(v0, w0[co],
                  fmaf(v1, w1r[co],
                  fmaf(v2, w2r[co], acc[co])));
    }
  }
  float* op = a2 + ((size_t)(b*H2 + oy)*H2 + ox)*C2 + cg16;
#pragma unroll
  for (int g = 0; g < 4; ++g) {
    float4 o;
    o.x = fmaxf(acc[4*g+0], 0.f);
    o.y = fmaxf(acc[4*g+1], 0.f);
    o.z = fmaxf(acc[4*g+2], 0.f);
    o.w = fmaxf(acc[4*g+3], 0.f);
    ((float4*)op)[g] = o;
  }
}

// ---------------------------------------------------------------- FC1 partial
// x = a2 flat [32, 262144]; w1 [262144, 128]. 1024 blocks, each owns a 256-k
// span. x chunk staged transposed in LDS (pad 36). Threads = [q 32 n-quads]
// [bo 8 b-quads]; acc = [4b][4n] = 16 regs -> no spill at the 64-VGPR budget.
#define FC1_G   1024
#define KSPAN   (K_FLAT / FC1_G)   // 256

__global__ __launch_bounds__(256)
void fc1_partial_k(const float* __restrict__ a2, const float* __restrict__ w1,
                   float* __restrict__ partial) {
  __shared__ __align__(16) float xT[KSPAN*36];   // 36,864 B
  const int tid = threadIdx.x;
  const int q   = tid & 31;    // n-quad: n = 4q..4q+3
  const int bo  = tid >> 5;    // 0..7 : b = 4bo..4bo+3
  const int k0  = blockIdx.x * KSPAN;

  // stage x chunk transposed: xT[k][b]
  {
    const int lb  = tid >> 3;    // 0..31
    const int lkq = tid & 7;
#pragma unroll
    for (int j = 0; j < 8; ++j) {
      const int k4 = lkq*4 + j*32;
      float4 t = *(const float4*)(a2 + (size_t)lb*K_FLAT + k0 + k4);
      xT[(k4+0)*36 + lb] = t.x;
      xT[(k4+1)*36 + lb] = t.y;
      xT[(k4+2)*36 + lb] = t.z;
      xT[(k4+3)*36 + lb] = t.w;
    }
  }
  __syncthreads();

  float4 a0 = make_float4(0.f,0.f,0.f,0.f), a1v = a0, a2v = a0, a3v = a0;
#pragma unroll 8
  for (int k = 0; k < KSPAN; ++k) {
    const float4 w4 = *(const float4*)(w1 + (size_t)(k0 + k)*NHID + 4*q);
    const float4 xb = *(const float4*)&xT[k*36 + 4*bo];
    a0.x = fmaf(xb.x, w4.x, a0.x); a0.y = fmaf(xb.x, w4.y, a0.y);
    a0.z = fmaf(xb.x, w4.z, a0.z); a0.w = fmaf(xb.x, w4.w, a0.w);
    a1v.x = fmaf(xb.y, w4.x, a1v.x); a1v.y = fmaf(xb.y, w4.y, a1v.y);
    a1v.z = fmaf(xb.y, w4.z, a1v.z); a1v.w = fmaf(xb.y, w4.w, a1v.w);
    a2v.x = fmaf(xb.z, w4.x, a2v.x); a2v.y = fmaf(xb.z, w4.y, a2v.y);
    a2v.z = fmaf(xb.z, w4.z, a2v.z); a2v.w = fmaf(xb.z, w4.w, a2v.w);
    a3v.x = fmaf(xb.w, w4.x, a3v.x); a3v.y = fmaf(xb.w, w4.y, a3v.y);
    a3v.z = fmaf(xb.w, w4.z, a3v.z); a3v.w = fmaf(xb.w, w4.w, a3v.w);
  }

  float* pp = partial + (size_t)blockIdx.x*(NB*NHID) + 4*q;
  *(float4*)(pp + (4*bo+0)*NHID) = a0;
  *(float4*)(pp + (4*bo+1)*NHID) = a1v;
  *(float4*)(pp + (4*bo+2)*NHID) = a2v;
  *(float4*)(pp + (4*bo+3)*NHID) = a3v;
}

// ---------------------------------------------------------------- FC1 reduce stage 1: 1024 -> 8
__global__ __launch_bounds__(128)
void fc1_reduce1_k(const float* __restrict__ partial, float* __restrict__ partial2) {
  const int t  = blockIdx.x*128 + threadIdx.x;  // 0..4095
  const int gc = blockIdx.y;                    // 0..7
  float s = 0.f;
#pragma unroll 8
  for (int g = gc*128; g < gc*128+128; ++g) s += partial[(size_t)g*(NB*NHID) + t];
  partial2[(size_t)gc*(NB*NHID) + t] = s;
}

// ---------------------------------------------------------------- FC1 reduce stage 2 (+bias+ReLU)
__global__ __launch_bounds__(256)
void fc1_reduce2_k(const float* __restrict__ partial2, const float* __restrict__ d1,
                   float* __restrict__ h) {
  const int t = blockIdx.x*256 + threadIdx.x;  // 0..4095
  float s = 0.f;
#pragma unroll
  for (int gc = 0; gc < 8; ++gc) s += partial2[(size_t)gc*(NB*NHID) + t];
  h[t] = fmaxf(s + d1[t & (NHID-1)], 0.f);
}

// ---------------------------------------------------------------- theta = h @ w2 + d2
__global__ __launch_bounds__(192)
void theta_k(const float* __restrict__ h, const float* __restrict__ w2,
             const float* __restrict__ d2, float* __restrict__ theta) {
  const int t = threadIdx.x;
  if (t >= NB*6) return;
  const int b = t / 6, j = t % 6;
  float s0 = 0.f, s1 = 0.f, s2 = 0.f, s3 = 0.f;
  for (int n = 0; n < NHID; n += 4) {
    s0 = fmaf(h[b*NHID + n+0], w2[(n+0)*6 + j], s0);
    s1 = fmaf(h[b*NHID + n+1], w2[(n+1)*6 + j], s1);
    s2 = fmaf(h[b*NHID + n+2], w2[(n+2)*6 + j], s2);
    s3 = fmaf(h[b*NHID + n+3], w2[(n+3)*6 + j], s3);
  }
  theta[t] = (s0 + s1) + (s2 + s3) + d2[j];
}

// ---------------------------------------------------------------- grid sample (bilinear, zero pad)
__global__ __launch_bounds__(256)
void sample_k(const float* __restrict__ img, const float* __restrict__ theta,
              float* __restrict__ out) {
  const int x = threadIdx.x;
  const int y = blockIdx.x & (IN_H-1);
  const int b = blockIdx.x >> 8;
  const float* tp = theta + b*6;
  const float t0 = tp[0], t1 = tp[1], t2 = tp[2];
  const float t3 = tp[3], t4 = tp[4], t5 = tp[5];

  const float xs = (2.f*x + 1.f)*(1.f/IN_W) - 1.f;
  const float ys = (2.f*y + 1.f)*(1.f/IN_H) - 1.f;
  const float gx = fmaf(t0, xs, fmaf(t1, ys, t2));
  const float gy = fmaf(t3, xs, fmaf(t4, ys, t5));
  const float px = fmaf(gx + 1.f, 0.5f*IN_W, -0.5f);
  const float py = fmaf(gy + 1.f, 0.5f*IN_H, -0.5f);

  const float x0f = floorf(px), y0f = floorf(py);
  const int ix0 = (int)x0f, iy0 = (int)y0f;
  const float wx1 = px - x0f, wx0 = 1.f - wx1;
  const float wy1 = py - y0f, wy0 = 1.f - wy1;

  float r = 0.f, g = 0.f, bl = 0.f;
  const float* ib = img + (size_t)b*IN_H*IN_W*C0;

  auto tap = [&](int yi, int xi, float w) {
    const bool v = (xi >= 0) && (xi < IN_W) && (yi >= 0) && (yi < IN_H);
    const int xc = xi < 0 ? 0 : (xi > IN_W-1 ? IN_W-1 : xi);
    const int yc = yi < 0 ? 0 : (yi > IN_H-1 ? IN_H-1 : yi);
    const float* p = ib + ((size_t)yc*IN_W + xc)*C0;
    if (v) {
      r  = fmaf(w, p[0], r);
      g  = fmaf(w, p[1], g);
      bl = fmaf(w, p[2], bl);
    }
  };
  tap(iy0,   ix0,   wy0*wx0);
  tap(iy0,   ix0+1, wy0*wx1);
  tap(iy0+1, ix0,   wy1*wx0);
  tap(iy0+1, ix0+1, wy1*wx1);

  float* op = out + ((size_t)(b*IN_H + y)*IN_W + x)*C0;
  op[0] = r; op[1] = g; op[2] = bl;
}

// ---------------------------------------------------------------- launch
extern "C" void kernel_launch(void* const* d_in, const int* in_sizes, int n_in,
                              void* d_out, int out_size, void* d_ws, size_t ws_size,
                              hipStream_t stream) {
  const float* in = (const float*)d_in[0];
  const float* k1 = (const float*)d_in[1];
  const float* b1 = (const float*)d_in[2];
  const float* k2 = (const float*)d_in[3];
  const float* b2 = (const float*)d_in[4];
  const float* w1 = (const float*)d_in[5];
  const float* d1 = (const float*)d_in[6];
  const float* w2 = (const float*)d_in[7];
  const float* d2 = (const float*)d_in[8];
  float* out = (float*)d_out;
  float* ws  = (float*)d_ws;

  // ws layout (float offsets):
  //   a1p      [16,777,216] @ 0               (planar, exactly 64 MB)
  //   a2       [ 8,388,608] @ 16,777,216      (NHWC, matches flatten order)
  //   -- after conv2, a1p region is dead and reused: --
  //   partial  [1024*4096 = 4,194,304] @ 0
  //   partial2 [8*4096    =    32,768] @ 4,194,304
  //   h        [4096]                  @ 4,227,072
  //   theta    [192]                   @ 4,231,168
  float* a1p     = ws;
  float* a2      = ws + (size_t)16777216;
  float* partial = ws;
  float* part2   = ws + (size_t)4194304;
  float* h       = ws + (size_t)4227072;
  float* th      = ws + (size_t)4231168;

  hipLaunchKernelGGL(conv1_k,       dim3(128, 32), dim3(256), 0, stream, in, k1, b1, a1p);
  hipLaunchKernelGGL(conv2_k,       dim3(64, 32),  dim3(256), 0, stream, a1p, k2, b2, a2);
  hipLaunchKernelGGL(fc1_partial_k, dim3(FC1_G),   dim3(256), 0, stream, a2, w1, partial);
  hipLaunchKernelGGL(fc1_reduce1_k, dim3(32, 8),   dim3(128), 0, stream, partial, part2);
  hipLaunchKernelGGL(fc1_reduce2_k, dim3(16),      dim3(256), 0, stream, part2, d1, h);
  hipLaunchKernelGGL(theta_k,       dim3(1),       dim3(192), 0, stream, h, w2, d2, th);
  hipLaunchKernelGGL(sample_k,      dim3(NB*IN_H), dim3(256), 0, stream, in, th, out);
}